// Round 17
// baseline (280.281 us; speedup 1.0000x reference)
//
#include <hip/hip_runtime.h>
#include <math.h>

#define BB 4
#define LL 512
#define DD 256
#define HH 8
#define DHH 32
#define NB 12  // BUCKETS + 1 (row 11 is the zero padding row)

typedef _Float16 half_t;
typedef __attribute__((ext_vector_type(2))) _Float16 half2v;
typedef __attribute__((ext_vector_type(4))) _Float16 half4;
typedef __attribute__((ext_vector_type(8))) _Float16 half8;
typedef __attribute__((ext_vector_type(4))) float f32x4;

// K1: QKV projections (round-16 exact). 8-row tiles, 768 blocks = 3 blocks/CU.
__global__ __launch_bounds__(256) void qkv_kernel(const float* __restrict__ x,
    const float* __restrict__ Wq, const float* __restrict__ bq,
    const float* __restrict__ Wk, const float* __restrict__ bk,
    const float* __restrict__ Wv, const float* __restrict__ bv,
    const float* __restrict__ uvec, const float* __restrict__ vvec,
    float* __restrict__ Qu, float* __restrict__ Qv,
    float* __restrict__ KT, float* __restrict__ V) {
    __shared__ float xs[8][DD];
    const int mat = blockIdx.x >> 8;          // 0=Q, 1=K, 2=V
    const int r0 = (blockIdx.x & 255) * 8;
    const int t = threadIdx.x;
    const int cg = t & 63, rg = t >> 6;
    const int c0 = cg * 4;
    {
        const float4* xg = (const float4*)(x + r0 * DD);
        float4* xsv = (float4*)&xs[0][0];
        xsv[t] = xg[t];
        xsv[t + 256] = xg[t + 256];
    }
    __syncthreads();
    const float* W    = (mat == 0) ? Wq : (mat == 1) ? Wk : Wv;
    const float* bias = (mat == 0) ? bq : (mat == 1) ? bk : bv;
    float acc[2][4];
#pragma unroll
    for (int r = 0; r < 2; ++r)
#pragma unroll
        for (int c = 0; c < 4; ++c) acc[r][c] = bias[c0 + c];
    for (int i0 = 0; i0 < DD; i0 += 8) {
        float4 wv4[8], xa[2], xb[2];
#pragma unroll
        for (int j = 0; j < 8; ++j) wv4[j] = *(const float4*)&W[(i0 + j) * DD + c0];
#pragma unroll
        for (int r = 0; r < 2; ++r) {
            xa[r] = *(const float4*)&xs[rg * 2 + r][i0];
            xb[r] = *(const float4*)&xs[rg * 2 + r][i0 + 4];
        }
#pragma unroll
        for (int r = 0; r < 2; ++r) {
            const float* xf = (const float*)&xa[r];
            const float* xg2 = (const float*)&xb[r];
#pragma unroll
            for (int j = 0; j < 4; ++j)
#pragma unroll
                for (int c = 0; c < 4; ++c)
                    acc[r][c] = fmaf(xf[j], ((const float*)&wv4[j])[c], acc[r][c]);
#pragma unroll
            for (int j = 0; j < 4; ++j)
#pragma unroll
                for (int c = 0; c < 4; ++c)
                    acc[r][c] = fmaf(xg2[j], ((const float*)&wv4[j + 4])[c], acc[r][c]);
        }
    }
    if (mat == 0) {
        const float s = 0.17677669529663687f;  // 1/sqrt(DH)
        const float4 u4 = *(const float4*)&uvec[c0];
        const float4 v4 = *(const float4*)&vvec[c0];
#pragma unroll
        for (int r = 0; r < 2; ++r) {
            const int row = r0 + rg * 2 + r;
            float4 q = make_float4(acc[r][0] * s, acc[r][1] * s, acc[r][2] * s, acc[r][3] * s);
            *(float4*)&Qu[row * DD + c0] = make_float4(q.x + u4.x, q.y + u4.y, q.z + u4.z, q.w + u4.w);
            *(float4*)&Qv[row * DD + c0] = make_float4(q.x + v4.x, q.y + v4.y, q.z + v4.z, q.w + v4.w);
        }
    } else if (mat == 1) {
        const int b = r0 >> 9;
        const int kb = (r0 & 511) + rg * 2;
#pragma unroll
        for (int c = 0; c < 4; ++c) {
            const int col = c0 + c;
            const int h = col >> 5, dd = col & 31;
            float* p = KT + ((long)((b * HH + h) * DHH + dd)) * LL + kb;
            p[0] = acc[0][c];
            p[1] = acc[1][c];
        }
    } else {
#pragma unroll
        for (int r = 0; r < 2; ++r)
            *(float4*)&V[(r0 + rg * 2 + r) * DD + c0] =
                make_float4(acc[r][0], acc[r][1], acc[r][2], acc[r][3]);
    }
}

// K2: fused rel-P + MFMA scores + softmax + attn write + ctx.
// Phase A (NEW, MFMA): K slice staged ONCE to LDS fp16 KsT[512][36]; scores =
// 4 mfma_f32_16x16x32_f16 per wave (wave w owns kcols [64w,64w+64)).
// Fragment layouts (m89/m120): A[m=lane&15][k=quad*8+j]; B[k=quad*8+j][n=lane&15];
// C/D row=quad*4+reg, col=lane&15. Epilogue keeps 16 e-values in regs (no spill),
// xor-shuffle row sums within 16-lane groups -> wsum[16][8] -> 1 barrier.
// Phase B (round-16 exact): fp16 Ss b128 + fp32 Vs chunks (Vs aliases dead KsT).
__global__ __launch_bounds__(512, 4) void scores_ctx_kernel(const float* __restrict__ Qu,
    const float* __restrict__ Qv, const float* __restrict__ KT,
    const float* __restrict__ rel_table, const int* __restrict__ mask,
    const int* __restrict__ dist, const float* __restrict__ V,
    float* __restrict__ attn, float* __restrict__ ctx) {
    __shared__ half_t Qsh[16][36];      // Qu fp16, stride 36 halves (b64-aligned frags)
    __shared__ half_t KsT[LL][36];      // K slice fp16 [kcol][d]; 36.9 KB
    __shared__ float rels[NB][DHH + 1];
    __shared__ float Ps[16][NB];
    __shared__ float wsum[16][8];
    __shared__ half_t Ss[16][4][136];   // attn tile fp16 (phase B layout, r16 exact)
    float (*Qvs)[DHH] = (float (*)[DHH])&Ss[0][0][0];   // 2 KB alias (dead before Ss use)
    float (*Vs)[133]  = (float (*)[133])&KsT[0][0];     // 17 KB alias (dead after MFMA)
    const int blk = blockIdx.x;         // ((b*32 + qt)*8 + h)
    const int h = blk & 7;
    const int rest = blk >> 3;
    const int qt = rest & 31;
    const int b = rest >> 5;
    const int q0 = qt * 16;
    const int t = threadIdx.x;
    const int w = t >> 6, l = t & 63;
    const int quad = l >> 4, lane16 = l & 15;
    const long kbase = (long)(b * HH + h) * DHH * LL;

    {   // stage Qu (fp16), Qv (fp32, aliased into Ss region)
        const int r = t >> 5, c = t & 31;
        Qsh[r][c] = (half_t)Qu[(b * LL + q0 + r) * DD + h * DHH + c];
        Qvs[r][c] = Qv[(b * LL + q0 + r) * DD + h * DHH + c];
    }
    if (t < NB * DHH) {
        rels[t >> 5][t & 31] = rel_table[(t >> 5) * DD + h * DHH + (t & 31)];
    }
    {   // stage K slice -> KsT[k][d] fp16 (coalesced b32 reads, half2 packed writes)
        const float* kg = KT + kbase + t;
#pragma unroll
        for (int dd = 0; dd < DHH; dd += 2) {
            const float v0 = kg[(long)dd * LL];
            const float v1 = kg[(long)(dd + 1) * LL];
            half2v hv = {(half_t)v0, (half_t)v1};
            *(half2v*)&KsT[t][dd] = hv;
        }
    }
    __syncthreads();
    if (t < 16 * NB) {                  // Ps[r][bk] = dot32(Qv[r], rels[bk]) in fp32
        const int bk = t >> 4, r = t & 15;
        float a = 0.f;
#pragma unroll
        for (int d = 0; d < DHH; ++d) a = fmaf(Qvs[r][d], rels[bk][d], a);
        Ps[r][bk] = a;
    }
    __syncthreads();

    // ---- Phase A: MFMA scores + softmax. Wave w: kcols [64w, 64w+64) ----
    half8 af;
    {
        const half4 a_lo = *(const half4*)&Qsh[lane16][quad * 8];
        const half4 a_hi = *(const half4*)&Qsh[lane16][quad * 8 + 4];
        af = __builtin_shufflevector(a_lo, a_hi, 0, 1, 2, 3, 4, 5, 6, 7);
    }
    float e_arr[4][4];                  // [ntile][reg]
#pragma unroll
    for (int nt = 0; nt < 4; ++nt) {
        const int kcb = (w * 4 + nt) * 16;          // tile's first kcol
        const half4 b_lo = *(const half4*)&KsT[kcb + lane16][quad * 8];
        const half4 b_hi = *(const half4*)&KsT[kcb + lane16][quad * 8 + 4];
        const half8 bf = __builtin_shufflevector(b_lo, b_hi, 0, 1, 2, 3, 4, 5, 6, 7);
        f32x4 acc = {0.f, 0.f, 0.f, 0.f};
        acc = __builtin_amdgcn_mfma_f32_16x16x32_f16(af, bf, acc, 0, 0, 0);
#pragma unroll
        for (int r = 0; r < 4; ++r) {
            const int row = quad * 4 + r;           // q row (C-layout)
            const int colg = kcb + lane16;          // k col
            const int mq = (b * LL + q0 + row) * LL + colg;
            e_arr[nt][r] = mask[mq] ? 0.f : __expf(acc[r] + Ps[row][dist[mq]]);
        }
    }
    // row sums: 16-lane xor reduce (cols), one LDS slot per (row, wave)
#pragma unroll
    for (int r = 0; r < 4; ++r) {
        float p = (e_arr[0][r] + e_arr[1][r]) + (e_arr[2][r] + e_arr[3][r]);
        for (int off = 8; off > 0; off >>= 1) p += __shfl_xor(p, off);
        if (lane16 == 0) wsum[quad * 4 + r][w] = p;
    }
    __syncthreads();
    {
        float inv[4];
#pragma unroll
        for (int r = 0; r < 4; ++r) {
            const float4 s0 = *(const float4*)&wsum[quad * 4 + r][0];   // broadcast
            const float4 s1 = *(const float4*)&wsum[quad * 4 + r][4];
            inv[r] = 1.0f / ((s0.x + s0.y + s0.z + s0.w) + (s1.x + s1.y + s1.z + s1.w));
        }
#pragma unroll
        for (int nt = 0; nt < 4; ++nt) {
            const int colg = (w * 4 + nt) * 16 + lane16;
            const int ch = colg >> 7, off = colg & 127;
#pragma unroll
            for (int r = 0; r < 4; ++r) {
                const int row = quad * 4 + r;
                const float a = e_arr[nt][r] * inv[r];
                attn[((long)(b * HH + h) * LL + q0 + row) * LL + colg] = a;
                Ss[row][ch][off] = (half_t)a;
            }
        }
    }

    // ---- Phase B: ctx via LDS-staged V chunks (round-16 exact; Vs aliases KsT) ----
    const int qB = t >> 5;              // 0..15
    const int dB = t & 31;
    const int kkS = t >> 2;             // staging row 0..127
    const int dqS = (t & 3) * 8;        // staging d-group of 8
    float acc = 0.f;
    for (int c = 0; c < 4; ++c) {
        __syncthreads();                // prev compute done; KsT dead -> Vs safe
        {   // stage V[b][c*128+kk][h*32+dq..dq+7] -> Vs[d][kk] (transposed)
            const float* vg = V + ((long)(b * LL + c * 128 + kkS)) * DD + h * DHH + dqS;
            const float4 va = *(const float4*)&vg[0];
            const float4 vb4 = *(const float4*)&vg[4];
            Vs[dqS + 0][kkS] = va.x;  Vs[dqS + 1][kkS] = va.y;
            Vs[dqS + 2][kkS] = va.z;  Vs[dqS + 3][kkS] = va.w;
            Vs[dqS + 4][kkS] = vb4.x; Vs[dqS + 5][kkS] = vb4.y;
            Vs[dqS + 6][kkS] = vb4.z; Vs[dqS + 7][kkS] = vb4.w;
        }
        __syncthreads();
#pragma unroll
        for (int j = 0; j < 16; ++j) {  // 8 k per iter: 1 Ss b128 + 2 Vs b128
            const half8 hv = *(const half8*)&Ss[qB][c][8 * j];     // broadcast b128
            const float4 v0 = *(const float4*)&Vs[dB][8 * j];      // conflict-free
            const float4 v1 = *(const float4*)&Vs[dB][8 * j + 4];
            acc = fmaf((float)hv[0], v0.x, fmaf((float)hv[1], v0.y,
                  fmaf((float)hv[2], v0.z, fmaf((float)hv[3], v0.w, acc))));
            acc = fmaf((float)hv[4], v1.x, fmaf((float)hv[5], v1.y,
                  fmaf((float)hv[6], v1.z, fmaf((float)hv[7], v1.w, acc))));
        }
    }
    ctx[(b * LL + q0 + qB) * DD + h * DHH + dB] = acc;
}

// K3: output projection (round-12 exact). Block = 4 rows; thread = 1 row x 4 cols.
__global__ __launch_bounds__(256) void outproj_kernel(const float* __restrict__ ctx,
    const float* __restrict__ Wo, const float* __restrict__ bo,
    float* __restrict__ out) {
    __shared__ float xs[4][DD];
    const int r0 = blockIdx.x * 4;
    const int t = threadIdx.x;
    const int rg = t >> 6;
    const int c0 = (t & 63) * 4;
    ((float4*)&xs[0][0])[t] = ((const float4*)(ctx + r0 * DD))[t];
    __syncthreads();
    float4 acc = *(const float4*)&bo[c0];
    for (int i0 = 0; i0 < DD; i0 += 8) {
        float4 wv[8];
#pragma unroll
        for (int j = 0; j < 8; ++j) wv[j] = *(const float4*)&Wo[(i0 + j) * DD + c0];
        const float4 x0 = *(const float4*)&xs[rg][i0];
        const float4 x1 = *(const float4*)&xs[rg][i0 + 4];
        const float* xf0 = (const float*)&x0;
        const float* xf1 = (const float*)&x1;
#pragma unroll
        for (int j = 0; j < 4; ++j) {
            acc.x = fmaf(xf0[j], wv[j].x, acc.x);
            acc.y = fmaf(xf0[j], wv[j].y, acc.y);
            acc.z = fmaf(xf0[j], wv[j].z, acc.z);
            acc.w = fmaf(xf0[j], wv[j].w, acc.w);
        }
#pragma unroll
        for (int j = 0; j < 4; ++j) {
            acc.x = fmaf(xf1[j], wv[j + 4].x, acc.x);
            acc.y = fmaf(xf1[j], wv[j + 4].y, acc.y);
            acc.z = fmaf(xf1[j], wv[j + 4].z, acc.z);
            acc.w = fmaf(xf1[j], wv[j + 4].w, acc.w);
        }
    }
    *(float4*)&out[(r0 + rg) * DD + c0] = acc;
}

extern "C" void kernel_launch(void* const* d_in, const int* in_sizes, int n_in,
                              void* d_out, int out_size, void* d_ws, size_t ws_size,
                              hipStream_t stream) {
    const float* x    = (const float*)d_in[0];
    const int* mk     = (const int*)d_in[1];   // jax bool -> int32
    const int* dist   = (const int*)d_in[2];
    const float* Wq = (const float*)d_in[3];
    const float* bq = (const float*)d_in[4];
    const float* Wk = (const float*)d_in[5];
    const float* bk = (const float*)d_in[6];
    const float* Wv = (const float*)d_in[7];
    const float* bv = (const float*)d_in[8];
    const float* Wo = (const float*)d_in[9];
    const float* bo = (const float*)d_in[10];
    const float* rel_table = (const float*)d_in[11];
    const float* uvec = (const float*)d_in[12];
    const float* vvec = (const float*)d_in[13];

    float* out  = (float*)d_out;                 // (B,L,D)
    float* attn = out + BB * LL * DD;            // (B,H,L,L)

    float* Qu = (float*)d_ws;                    // q/sqrt(dh) + u
    float* Qv = Qu + BB * LL * DD;               // q/sqrt(dh) + v
    float* KT = Qv + BB * LL * DD;               // [B][H][DH][L]
    float* V  = KT + BB * LL * DD;               // [B][L][D]
    float* C  = V + BB * LL * DD;                // ctx (B,L,D); 10.5 MB ws total

    qkv_kernel<<<3 * 256, 256, 0, stream>>>(x, Wq, bq, Wk, bk, Wv, bv, uvec, vvec,
                                            Qu, Qv, KT, V);
    scores_ctx_kernel<<<BB * (LL / 16) * HH, 512, 0, stream>>>(Qu, Qv, KT, rel_table,
                                                               mk, dist, V, attn, C);
    outproj_kernel<<<BB * LL / 4, 256, 0, stream>>>(C, Wo, bo, out);
}